// Round 10
// baseline (206.651 us; speedup 1.0000x reference)
//
#include <hip/hip_runtime.h>

// HierarchicalTimeAttention  B=4, T=4096, H=1024, D=4
// R10: 4-phase schedule (R8) x counted vmcnt (R9) — the m218/m196 conjunction.
// Quarter-tile FIFO staging: P1 issues A-q0,q2(t+1), P2: B0,B1(t+1),
// P3: B2,B3(t+1), P4: A-q1,q3(t+1). Waits: vmcnt(2) at P4-end (A-q1,q3 fly
// across tile boundary), vmcnt(4) at P2-end (drains A-q1,q3 of cur tile).
// Never vmcnt(0) in main loop (tail peeled).
// R8: 4-phase + drain0 = 50.6us; R9: 1-phase + counted = 51.0us; MfmaUtil 25%.
#define B_ 4
#define T_ 4096
#define H_ 1024
#define D_ 4
#define M_ (B_ * T_)          // 16384
#define OUT_MAIN (M_ * H_)    // 16,777,216 (f32 elements)

// ws (bytes), total ~40.3MB:
#define WS_BUF  0UL           // bf16 [M][H]: k -> kv -> o   (32MB)
#define WS_WK   33554432UL    // bf16 Wk,Wv,Wr,Wo contiguous [4][H][H] (8MB)
#define WS_LGW  41943040UL    // f32 softmax weights [M][4] (256KB)
#define WS_DEC  42205184UL    // f32 decayed_state0 [B][D][H] (64KB)

typedef __bf16 bf16x8 __attribute__((ext_vector_type(8)));
typedef unsigned short u16x4 __attribute__((ext_vector_type(4)));
typedef float f32x4 __attribute__((ext_vector_type(4)));

__device__ __forceinline__ float b2f(unsigned short u) {
    union { unsigned int i; float f; } c;
    c.i = ((unsigned int)u) << 16;
    return c.f;
}
__device__ __forceinline__ unsigned short f2b(float f) {
    union { float f; unsigned int i; } c;
    c.f = f;
    unsigned int x = c.i;
    unsigned int r = (x + 0x7FFFu + ((x >> 16) & 1u)) >> 16;  // RNE
    return (unsigned short)r;
}

#define BAR()  asm volatile("s_barrier" ::: "memory")
#define GLLDS(gsrc, ldst)                                                     \
    __builtin_amdgcn_global_load_lds(                                         \
        (const __attribute__((address_space(1))) unsigned int*)(gsrc),        \
        (__attribute__((address_space(3))) unsigned int*)(ldst), 16, 0, 0)

// ---------------------------------------------------------------------------
// f32 -> bf16 conversions
// ---------------------------------------------------------------------------
__global__ __launch_bounds__(256) void cvt_k(const float* __restrict__ s,
                                             unsigned short* __restrict__ d, int n4)
{
    int i = blockIdx.x * 256 + threadIdx.x;
    const int str = gridDim.x * 256;
    for (; i < n4; i += str) {
        const f32x4 v = ((const f32x4*)s)[i];
        u16x4 o;
        o[0] = f2b(v[0]); o[1] = f2b(v[1]); o[2] = f2b(v[2]); o[3] = f2b(v[3]);
        ((u16x4*)d)[i] = o;
    }
}

// 4 weight matrices in one dispatch: grid (1024, 4), dst contiguous [4][H][H]
__global__ __launch_bounds__(256) void cvtw_k(
    const float* __restrict__ s0, const float* __restrict__ s1,
    const float* __restrict__ s2, const float* __restrict__ s3,
    unsigned short* __restrict__ d)
{
    const int w = blockIdx.y;
    const float* s = (w == 0) ? s0 : (w == 1) ? s1 : (w == 2) ? s2 : s3;
    const int i = blockIdx.x * 256 + threadIdx.x;
    const f32x4 v = ((const f32x4*)s)[i];
    u16x4 o;
    o[0] = f2b(v[0]); o[1] = f2b(v[1]); o[2] = f2b(v[2]); o[3] = f2b(v[3]);
    ((u16x4*)(d + (size_t)w * (H_ * H_)))[i] = o;
}

// ---------------------------------------------------------------------------
// GEMM: C[16384][1024] = A[16384][1024] @ W[1024][1024]^T  (bf16, f32 acc)
// 256x256 tile, 8 waves (2Mx4N, 128x64/wave), BK=64, dbuf LDS 128KB.
// 4 phases per K-tile, quadrant order (mi03xni01, mi03xni23, mi47xni23,
// mi47xni01). Quarter-tile staging in FIFO consumption order (see header).
// Swizzle: phys_granule = g ^ (row&7) within 8x16B rows; staged via
// inverse-swizzled global source, read back with same XOR (conflicts = 0,
// validated R8). A/B frag: row(col)=lane&15, k=8*(lane>>4)+i ; C/D:
// col=lane&15, row=4*(lane>>4)+reg  [verified r2==r4 agreement]
// EPI 0: C = bf16(acc)        EPI 1: C = bf16(acc * C)   (in-place)
// EPI 2: C = bf16(sigmoid(acc)*(lw.dec + wsum*C))        (in-place)
// EPI 3: outf = acc (f32)
// ---------------------------------------------------------------------------
template <int EPI>
__global__ __launch_bounds__(512, 2) void gemm8c(
    const unsigned short* __restrict__ A,
    const unsigned short* __restrict__ Wt,
    unsigned short* C,
    float* __restrict__ outf,
    const float* __restrict__ lgw,
    const float* __restrict__ dec)
{
    __shared__ __align__(16) unsigned short As[2 * 16384];  // 2 bufs x 256x64
    __shared__ __align__(16) unsigned short Bs[2 * 16384];

    const int tid  = threadIdx.x;
    const int wid  = tid >> 6;        // 0..7
    const int lane = tid & 63;
    const int l15  = lane & 15;
    const int q    = lane >> 4;       // 0..3
    const int wrow = wid >> 2;        // 0..1  (128-row half)
    const int wcol = wid & 3;         // 0..3  (64-col quarter)
    const int brow = blockIdx.x * 256;
    const int bcol = blockIdx.y * 256;

    // staging: call i stages quarter rows [i*64, i*64+64). Thread handles
    // granule G = i*512 + tid: LDS row = G>>3, phys g = G&7; global source
    // granule cg = phys ^ (row&7)  (inverse swizzle).
    int offA[4], offB[4], dstq[4];
#pragma unroll
    for (int i = 0; i < 4; ++i) {
        const int G   = i * 512 + tid;
        const int row = G >> 3;
        const int cg  = (G & 7) ^ (row & 7);
        offA[i] = (brow + row) * 1024 + cg * 8;
        offB[i] = (bcol + row) * 1024 + cg * 8;
        dstq[i] = G * 8;
    }

    // ds_read offsets: logical granule g = ks*4+q, phys = g ^ (row&7), and
    // row&7 = lane&7 for all frag rows (row base multiple of 16).
    int gx[2];
#pragma unroll
    for (int ks = 0; ks < 2; ++ks) gx[ks] = ((ks * 4 + q) ^ (lane & 7)) * 8;
    int aB[8], bB[4];
#pragma unroll
    for (int mi = 0; mi < 8; ++mi) aB[mi] = (wrow * 128 + mi * 16 + l15) * 64;
#pragma unroll
    for (int ni = 0; ni < 4; ++ni) bB[ni] = (wcol * 64 + ni * 16 + l15) * 64;

    f32x4 acc[8][4];
#pragma unroll
    for (int i = 0; i < 8; ++i)
#pragma unroll
        for (int j = 0; j < 4; ++j)
            acc[i][j] = (f32x4){0.f, 0.f, 0.f, 0.f};

#define GA(bo, kk, i_) GLLDS(A  + offA[i_] + (kk), As + (bo) + dstq[i_])
#define GB(bo, kk, i_) GLLDS(Wt + offB[i_] + (kk), Bs + (bo) + dstq[i_])
#define RD_A(MB)                                                              \
    _Pragma("unroll") for (int mi = 0; mi < 4; ++mi)                          \
    _Pragma("unroll") for (int ks = 0; ks < 2; ++ks)                          \
        aR[mi][ks] = *(const bf16x8*)&As[cur + aB[(MB) + mi] + gx[ks]];
#define RD_B(N0)                                                              \
    _Pragma("unroll") for (int ni = 0; ni < 2; ++ni)                          \
    _Pragma("unroll") for (int ks = 0; ks < 2; ++ks)                          \
        bR[(N0) + ni][ks] = *(const bf16x8*)&Bs[cur + bB[(N0) + ni] + gx[ks]];
#define MFMA_Q(MB, NB)                                                        \
    __builtin_amdgcn_s_setprio(1);                                            \
    _Pragma("unroll") for (int mi = 0; mi < 4; ++mi)                          \
    _Pragma("unroll") for (int ni = 0; ni < 2; ++ni)                          \
    _Pragma("unroll") for (int ks = 0; ks < 2; ++ks)                          \
        acc[(MB) + mi][(NB) + ni] = __builtin_amdgcn_mfma_f32_16x16x32_bf16(  \
            aR[mi][ks], bR[(NB) + ni][ks], acc[(MB) + mi][(NB) + ni], 0, 0, 0);\
    __builtin_amdgcn_s_setprio(0);

    // --- prologue: stage tile 0, FIFO = {Aq0,Aq2,B0,B1,B2,B3} then {Aq1,Aq3}
    GA(0, 0, 0); GA(0, 0, 2);
    GB(0, 0, 0); GB(0, 0, 1); GB(0, 0, 2); GB(0, 0, 3);
    GA(0, 0, 1); GA(0, 0, 3);
    asm volatile("s_waitcnt vmcnt(2)" ::: "memory");
    BAR();

    // --- main loop: tiles 0..14 (stage tile t+1)
#pragma unroll 1
    for (int t = 0; t < 15; ++t) {
        const int cur = (t & 1) << 14;
        const int nxt = cur ^ 16384;
        const int kk  = (t + 1) * 64;
        bf16x8 aR[4][2], bR[4][2];

        // P1: reads a(mi0-3)+b(ni0-1); stage A-q0,q2(t+1)
        RD_A(0); RD_B(0);
        GA(nxt, kk, 0); GA(nxt, kk, 2);
        BAR();
        MFMA_Q(0, 0);
        BAR();

        // P2: reads b(ni2-3); stage B0,B1(t+1); gate A-q1,q3(t)
        RD_B(2);
        GB(nxt, kk, 0); GB(nxt, kk, 1);
        BAR();
        MFMA_Q(0, 2);
        asm volatile("s_waitcnt vmcnt(4)" ::: "memory");
        BAR();

        // P3: reads a(mi4-7); stage B2,B3(t+1)
        RD_A(4);
        GB(nxt, kk, 2); GB(nxt, kk, 3);
        BAR();
        MFMA_Q(4, 2);
        BAR();

        // P4: stage A-q1,q3(t+1); gate everything t+1-P1 needs
        GA(nxt, kk, 1); GA(nxt, kk, 3);
        BAR();
        MFMA_Q(4, 0);
        asm volatile("s_waitcnt vmcnt(2)" ::: "memory");
        BAR();
    }

    // --- tail: tile 15 (no staging)
    {
        const int cur = 16384;
        bf16x8 aR[4][2], bR[4][2];
        RD_A(0); RD_B(0);
        BAR();
        MFMA_Q(0, 0);
        BAR();
        RD_B(2);
        BAR();
        MFMA_Q(0, 2);
        asm volatile("s_waitcnt vmcnt(0)" ::: "memory");
        BAR();
        RD_A(4);
        BAR();
        MFMA_Q(4, 2);
        BAR();
        BAR();
        MFMA_Q(4, 0);
    }
#undef GA
#undef GB
#undef RD_A
#undef RD_B
#undef MFMA_Q

    // ---- epilogue
    const int orow0 = brow + wrow * 128;
    const int ocol0 = bcol + wcol * 64;
    const int rbase = q * 4;
    if (EPI == 0) {
#pragma unroll
        for (int mi = 0; mi < 8; ++mi)
#pragma unroll
            for (int j = 0; j < 4; ++j) {
                const size_t r = (size_t)(orow0 + mi * 16 + rbase + j);
#pragma unroll
                for (int ni = 0; ni < 4; ++ni)
                    C[r * 1024 + (ocol0 + ni * 16 + l15)] = f2b(acc[mi][ni][j]);
            }
    } else if (EPI == 1) {
#pragma unroll
        for (int mi = 0; mi < 8; ++mi)
#pragma unroll
            for (int j = 0; j < 4; ++j) {
                const size_t r = (size_t)(orow0 + mi * 16 + rbase + j);
#pragma unroll
                for (int ni = 0; ni < 4; ++ni) {
                    const size_t idx = r * 1024 + (ocol0 + ni * 16 + l15);
                    C[idx] = f2b(acc[mi][ni][j] * b2f(C[idx]));
                }
            }
    } else if (EPI == 2) {
        const int b = brow >> 12;   // 256-row blocks never straddle a batch
        float dcol[4][4];
#pragma unroll
        for (int ni = 0; ni < 4; ++ni)
#pragma unroll
            for (int d = 0; d < 4; ++d)
                dcol[ni][d] = dec[b * (D_ * H_) + d * H_ + (ocol0 + ni * 16 + l15)];
#pragma unroll
        for (int mi = 0; mi < 8; ++mi)
#pragma unroll
            for (int j = 0; j < 4; ++j) {
                const int r = orow0 + mi * 16 + rbase + j;
                const f32x4 lw = *(const f32x4*)(lgw + (size_t)r * 4);
                const float wsum = lw[0] + lw[1] + lw[2] + lw[3];
#pragma unroll
                for (int ni = 0; ni < 4; ++ni) {
                    const size_t idx = (size_t)r * 1024 + (ocol0 + ni * 16 + l15);
                    const float rv = 1.0f / (1.0f + __expf(-acc[mi][ni][j]));
                    const float w  = lw[0] * dcol[ni][0] + lw[1] * dcol[ni][1]
                                   + lw[2] * dcol[ni][2] + lw[3] * dcol[ni][3]
                                   + wsum * b2f(C[idx]);
                    C[idx] = f2b(rv * w);
                }
            }
    } else {
#pragma unroll
        for (int mi = 0; mi < 8; ++mi)
#pragma unroll
            for (int j = 0; j < 4; ++j) {
                const size_t r = (size_t)(orow0 + mi * 16 + rbase + j);
#pragma unroll
                for (int ni = 0; ni < 4; ++ni)
                    outf[r * 1024 + (ocol0 + ni * 16 + l15)] = acc[mi][ni][j];
            }
    }
}

// ---------------------------------------------------------------------------
// lgw[row][0..3] = softmax(x @ Wl^T + bl), one wave per row, f32.
// ---------------------------------------------------------------------------
__global__ __launch_bounds__(256) void logits_k(
    const float* __restrict__ X, const float* __restrict__ Wl,
    const float* __restrict__ bl, float* __restrict__ lgw)
{
    const int wid  = threadIdx.x >> 6;
    const int lane = threadIdx.x & 63;
    const int row  = blockIdx.x * 4 + wid;
    const float* xp = X + (size_t)row * H_;

    float acc[D_] = {0.f, 0.f, 0.f, 0.f};
    for (int h = lane * 4; h < H_; h += 256) {
        const f32x4 xv = *(const f32x4*)(xp + h);
#pragma unroll
        for (int d = 0; d < D_; ++d) {
            const f32x4 wv = *(const f32x4*)(Wl + d * H_ + h);
            acc[d] += xv[0] * wv[0] + xv[1] * wv[1] + xv[2] * wv[2] + xv[3] * wv[3];
        }
    }
#pragma unroll
    for (int off = 32; off; off >>= 1)
#pragma unroll
        for (int d = 0; d < D_; ++d) acc[d] += __shfl_xor(acc[d], off, 64);

    if (lane == 0) {
        float l[D_];
#pragma unroll
        for (int d = 0; d < D_; ++d) l[d] = acc[d] + bl[d];
        const float mx = fmaxf(fmaxf(l[0], l[1]), fmaxf(l[2], l[3]));
        float e[D_], s = 0.f;
#pragma unroll
        for (int d = 0; d < D_; ++d) { e[d] = __expf(l[d] - mx); s += e[d]; }
        const float inv = 1.0f / s;
        f32x4 o;
#pragma unroll
        for (int d = 0; d < D_; ++d) o[d] = e[d] * inv;
        *(f32x4*)(lgw + (size_t)row * 4) = o;
    }
}

// ---------------------------------------------------------------------------
__global__ void decstate_k(const float* __restrict__ state,
                           const float* __restrict__ tdm,
                           float* __restrict__ dec)
{
    const int i = blockIdx.x * blockDim.x + threadIdx.x;
    if (i >= B_ * D_ * H_) return;
    const int dh = i & (D_ * H_ - 1);
    dec[i] = state[i] * __expf(-__expf(tdm[dh]));
}

// ---------------------------------------------------------------------------
// new_state[b,d,h] = dec[b,d,h] + k_last*v_last, all-f32 exact path.
// ---------------------------------------------------------------------------
__global__ __launch_bounds__(256) void newstate_k(
    const float* __restrict__ X, const float* __restrict__ Wk,
    const float* __restrict__ Wv, const float* __restrict__ dec,
    float* __restrict__ out2)
{
    const int wid  = threadIdx.x >> 6;
    const int lane = threadIdx.x & 63;
    const int row  = blockIdx.x * 4 + wid;   // 0..B*H-1
    const int b    = row >> 10;
    const int h    = row & (H_ - 1);
    const float* xp = X + ((size_t)(b * T_ + (T_ - 1))) * H_;

    float ak = 0.f, av = 0.f;
    for (int j = lane * 4; j < H_; j += 256) {
        const f32x4 xv = *(const f32x4*)(xp + j);
        const f32x4 wk = *(const f32x4*)(Wk + (size_t)h * H_ + j);
        const f32x4 wv = *(const f32x4*)(Wv + (size_t)h * H_ + j);
        ak += xv[0]*wk[0] + xv[1]*wk[1] + xv[2]*wk[2] + xv[3]*wk[3];
        av += xv[0]*wv[0] + xv[1]*wv[1] + xv[2]*wv[2] + xv[3]*wv[3];
    }
#pragma unroll
    for (int off = 32; off; off >>= 1) {
        ak += __shfl_xor(ak, off, 64);
        av += __shfl_xor(av, off, 64);
    }
    if (lane == 0) {
        const float kv = ak * av;
#pragma unroll
        for (int d = 0; d < D_; ++d)
            out2[(size_t)(b * D_ + d) * H_ + h] = dec[(b * D_ + d) * H_ + h] + kv;
    }
}

// ---------------------------------------------------------------------------
extern "C" void kernel_launch(void* const* d_in, const int* in_sizes, int n_in,
                              void* d_out, int out_size, void* d_ws, size_t ws_size,
                              hipStream_t stream)
{
    const float* x   = (const float*)d_in[0];
    const float* st  = (const float*)d_in[1];
    const float* tdm = (const float*)d_in[2];
    const float* Wl  = (const float*)d_in[3];
    const float* bl  = (const float*)d_in[4];
    const float* Wv  = (const float*)d_in[5];
    const float* Wk  = (const float*)d_in[6];
    const float* Wr  = (const float*)d_in[7];
    const float* Wo  = (const float*)d_in[8];
    float* out = (float*)d_out;                    // f32 output

    char* ws = (char*)d_ws;
    unsigned short* buf  = (unsigned short*)(ws + WS_BUF);   // k -> kv -> o
    unsigned short* wk_b = (unsigned short*)(ws + WS_WK);    // [4][H][H]: k,v,r,o
    unsigned short* wv_b = wk_b + 1 * (H_ * H_);
    unsigned short* wr_b = wk_b + 2 * (H_ * H_);
    unsigned short* wo_b = wk_b + 3 * (H_ * H_);
    float* lgw = (float*)(ws + WS_LGW);
    float* dec = (float*)(ws + WS_DEC);

    // bf16 x scratch inside d_out's f32 output-0 region; final GEMM
    // fully overwrites it afterwards.
    unsigned short* xb = (unsigned short*)out;

    // small f32 kernels (depend only on raw inputs)
    logits_k<<<M_ / 4, 256, 0, stream>>>(x, Wl, bl, lgw);
    decstate_k<<<(B_ * D_ * H_ + 255) / 256, 256, 0, stream>>>(st, tdm, dec);
    newstate_k<<<(B_ * H_) / 4, 256, 0, stream>>>(x, Wk, Wv, dec, out + OUT_MAIN);

    // conversions
    cvt_k<<<2048, 256, 0, stream>>>(x, xb, OUT_MAIN / 4);
    cvtw_k<<<dim3(1024, 4), 256, 0, stream>>>(Wk, Wv, Wr, Wo, wk_b);

    const dim3 g(M_ / 256, H_ / 256), blk(512);

    // buf = k
    hipLaunchKernelGGL((gemm8c<0>), g, blk, 0, stream, xb, wk_b, buf,
                       (float*)nullptr, (const float*)nullptr, (const float*)nullptr);
    // buf = kv
    hipLaunchKernelGGL((gemm8c<1>), g, blk, 0, stream, xb, wv_b, buf,
                       (float*)nullptr, (const float*)nullptr, (const float*)nullptr);
    // buf = o = sigmoid(x@Wr^T) * (lw.dec + wsum*kv)
    hipLaunchKernelGGL((gemm8c<2>), g, blk, 0, stream, xb, wr_b, buf,
                       (float*)nullptr, (const float*)lgw, (const float*)dec);
    // out = f32(o @ Wo^T)
    hipLaunchKernelGGL((gemm8c<3>), g, blk, 0, stream, buf, wo_b, (unsigned short*)nullptr,
                       out, (const float*)nullptr, (const float*)nullptr);
}